// Round 2
// 106.154 us; speedup vs baseline: 1.0420x; 1.0420x over previous
//
#include <hip/hip_runtime.h>
#include <math.h>

#define NN 1024
#define HH 128

typedef _Float16 h2 __attribute__((ext_vector_type(2)));
typedef _Float16 h4 __attribute__((ext_vector_type(4)));
typedef _Float16 h8 __attribute__((ext_vector_type(8)));

__device__ inline float fdot2(h2 a, h2 b, float c) {
  return __builtin_amdgcn_fdot2(a, b, c, false);
}

// ---------------------------------------------------------------- qkv ------
// grid 257 x 512. Blocks 0..255: 4 rows, mat = t>>7 in {q,k,v,P}.
// P[j] = x[j] @ We1  (NO bias; bias folded on the i-side in attn).
// KP layout: [HH/2][NN/2] h8 blocks (16 B):
//   halves 0..3 = {K[j0][c0],K[j0][c1],K[j1][c0],K[j1][c1]}
//   halves 4..7 = {P[j0][c0],P[j0][c1],P[j1][c0],P[j1][c1]}   (j0=2*j2, c0=2*u)
// VP layout: [NN/4][HH/2] h8 blocks:
//   {V[j0][c0],V[j1][c0],V[j0][c1],V[j1][c1],V[j2][c0],V[j3][c0],V[j2][c1],V[j3][c1]}
// q is written pre-scaled by 1/sqrt(128).
// Block 256: Wc2/bc2 fold.
__global__ __launch_bounds__(512) void qkv_kernel(
    const float* __restrict__ h, const float* __restrict__ x,
    const float* __restrict__ Wq, const float* __restrict__ bq,
    const float* __restrict__ Wk, const float* __restrict__ bk,
    const float* __restrict__ Wv, const float* __restrict__ bv,
    const float* __restrict__ We1,
    const float* __restrict__ We2, const float* __restrict__ be2,
    const float* __restrict__ Wc, const float* __restrict__ bc,
    float* __restrict__ q, _Float16* __restrict__ KP,
    _Float16* __restrict__ VP, float* __restrict__ Wc2,
    float* __restrict__ bc2) {
  const int t = threadIdx.x;

  if (blockIdx.x == 256) {  // ---- wc2 fold ----
    if (t < HH) {
      float a = 0.f;
      for (int d = 0; d < HH; ++d) a = fmaf(We2[t * HH + d], Wc[d], a);
      Wc2[t] = a;
      if (t == 0) {
        float b = bc[0];
        for (int d = 0; d < HH; ++d) b = fmaf(be2[d], Wc[d], b);
        *bc2 = b;
      }
    }
    return;
  }

  __shared__ float4 hs4[HH];
  __shared__ float xsh[8];
  const int r0 = blockIdx.x * 4;
  if (t < HH) {
    hs4[t] = make_float4(h[(r0 + 0) * HH + t], h[(r0 + 1) * HH + t],
                         h[(r0 + 2) * HH + t], h[(r0 + 3) * HH + t]);
  }
  if (t >= HH && t < HH + 8) xsh[t - HH] = x[r0 * 2 + (t - HH)];
  __syncthreads();

  const int mat = t >> 7;  // 0=q 1=k 2=v 3=P
  const int col = t & 127;

  if (mat == 3) {  // ---- P = x @ We1 (f32, round once to f16) ----
    const float w0 = We1[col], w1 = We1[HH + col];
    const int base = ((col >> 1) * (NN / 2) + (r0 >> 1)) * 8 + 4 + (col & 1);
#pragma unroll
    for (int rr = 0; rr < 4; ++rr) {
      float p = fmaf(xsh[2 * rr], w0, xsh[2 * rr + 1] * w1);
      KP[base + (rr >> 1) * 8 + (rr & 1) * 2] = (_Float16)p;
    }
    return;
  }

  const float* W = (mat == 0) ? Wq : (mat == 1) ? Wk : Wv;
  const float* B = (mat == 0) ? bq : (mat == 1) ? bk : bv;
  const float b = B[col];
  float a0 = b, a1 = b, a2 = b, a3 = b;
#pragma unroll 8
  for (int c = 0; c < HH; ++c) {
    float w = W[c * HH + col];
    float4 hv = hs4[c];
    a0 = fmaf(hv.x, w, a0);
    a1 = fmaf(hv.y, w, a1);
    a2 = fmaf(hv.z, w, a2);
    a3 = fmaf(hv.w, w, a3);
  }
  if (mat == 0) {
    const float scale = 0.08838834764831845f;  // 1/sqrt(128) folded into q
    q[(r0 + 0) * HH + col] = a0 * scale;
    q[(r0 + 1) * HH + col] = a1 * scale;
    q[(r0 + 2) * HH + col] = a2 * scale;
    q[(r0 + 3) * HH + col] = a3 * scale;
  } else if (mat == 1) {
    const int base = ((col >> 1) * (NN / 2) + (r0 >> 1)) * 8 + (col & 1);
    KP[base + 0] = (_Float16)a0;   // rr=0
    KP[base + 2] = (_Float16)a1;   // rr=1
    KP[base + 8] = (_Float16)a2;   // rr=2
    KP[base + 10] = (_Float16)a3;  // rr=3
  } else {
    const int base = ((r0 >> 2) * (HH / 2) + (col >> 1)) * 8 + (col & 1) * 2;
    VP[base + 0] = (_Float16)a0;  // rr=0
    VP[base + 1] = (_Float16)a1;  // rr=1
    VP[base + 4] = (_Float16)a2;  // rr=2
    VP[base + 5] = (_Float16)a3;  // rr=3
  }
}

// ------------------------------------------------------------- attn --------
// grid 512 x 512; block = 2 query rows; thread t owns j in {2t, 2t+1}.
// Edge-MLP pre-activation is separable: relu((xi-xj)@We1 + be1)
//   = relu((P_i + be1) - P_j) — P precomputed; hot loop does 1 pk_sub
//   instead of 2 pk_fma per pair per channel-pair.
__global__ __launch_bounds__(512) void attn_kernel(
    const float* __restrict__ h, const float* __restrict__ x,
    const float* __restrict__ q, const h8* __restrict__ KP,
    const h8* __restrict__ VP, const float* __restrict__ be1,
    const float* __restrict__ Wc2p, const float* __restrict__ bc2p,
    float* __restrict__ out) {
  __shared__ h8 qpp[HH / 2];   // {q_i0 cpair, q_i1 cpair, P'_i0 cpair, P'_i1 cpair}
  __shared__ h2 ccs[HH / 2];   // Wc2 cpair
  __shared__ h4 wspi[NN / 2];  // (e00,e01,e10,e11) per j2
  __shared__ float xs[NN * 2];
  __shared__ float part[8][2][HH];
  __shared__ float red[6][8];

  const int i0 = blockIdx.x * 2, i1 = i0 + 1;
  const int tid = threadIdx.x;
  const int lane = tid & 63, wave = tid >> 6;  // 8 waves

  if (tid < HH / 2) {
    const int u = tid;
    float2 qa = *(const float2*)(q + i0 * HH + 2 * u);
    float2 qb = *(const float2*)(q + i1 * HH + 2 * u);
    h8 kp = KP[u * (NN / 2) + (i0 >> 1)];  // halves 4..7 = P rows i0,i1
    float2 b1 = *(const float2*)(be1 + 2 * u);
    h8 a;
    a[0] = (_Float16)qa.x; a[1] = (_Float16)qa.y;
    a[2] = (_Float16)qb.x; a[3] = (_Float16)qb.y;
    a[4] = (_Float16)((float)kp[4] + b1.x);
    a[5] = (_Float16)((float)kp[5] + b1.y);
    a[6] = (_Float16)((float)kp[6] + b1.x);
    a[7] = (_Float16)((float)kp[7] + b1.y);
    qpp[u] = a;
    h2 c;
    c.x = (_Float16)Wc2p[2 * u];
    c.y = (_Float16)Wc2p[2 * u + 1];
    ccs[u] = c;
  }
  for (int j = tid; j < NN * 2; j += 512) xs[j] = x[j];
  const float bc2 = *bc2p;
  __syncthreads();

  // rel coords for this thread's 4 (i,j) pairs (f32, for delta_x)
  const float xi0x = xs[2 * i0], xi0y = xs[2 * i0 + 1];
  const float xi1x = xs[2 * i1], xi1y = xs[2 * i1 + 1];
  const int j0 = 2 * tid, j1 = j0 + 1;
  const float xj0x = xs[2 * j0], xj0y = xs[2 * j0 + 1];
  const float xj1x = xs[2 * j1], xj1y = xs[2 * j1 + 1];
  const float rx00 = xi0x - xj0x, ry00 = xi0y - xj0y;
  const float rx01 = xi0x - xj1x, ry01 = xi0y - xj1y;
  const float rx10 = xi1x - xj0x, ry10 = xi1y - xj0y;
  const float rx11 = xi1x - xj1x, ry11 = xi1y - xj1y;

  h2 Z2;
  Z2.x = Z2.y = (_Float16)0;

  // ---- Fused phase: scores + gate. Per u: 1 dwordx4 + 1 b128 + 1 b32,
  //      16 VALU (4 dot2 scores, 4 pk_sub, 4 pk_max, 4 dot2 gate).
  float s00 = 0.f, s01 = 0.f, s10 = 0.f, s11 = 0.f;
  float g00 = bc2, g01 = bc2, g10 = bc2, g11 = bc2;
  const h8* kptr = KP + tid;
#pragma unroll 4
  for (int u = 0; u < HH / 2; ++u) {
    h8 kp = kptr[u * (NN / 2)];
    h8 qp = qpp[u];
    h2 cc = ccs[u];
    h2 ka, kb, pj0, pj1, q0, q1, pi0, pi1;
    ka.x = kp[0]; ka.y = kp[1];
    kb.x = kp[2]; kb.y = kp[3];
    pj0.x = kp[4]; pj0.y = kp[5];
    pj1.x = kp[6]; pj1.y = kp[7];
    q0.x = qp[0]; q0.y = qp[1];
    q1.x = qp[2]; q1.y = qp[3];
    pi0.x = qp[4]; pi0.y = qp[5];
    pi1.x = qp[6]; pi1.y = qp[7];
    s00 = fdot2(q0, ka, s00);
    s01 = fdot2(q0, kb, s01);
    s10 = fdot2(q1, ka, s10);
    s11 = fdot2(q1, kb, s11);
    h2 t00 = __builtin_elementwise_max(pi0 - pj0, Z2);
    h2 t01 = __builtin_elementwise_max(pi0 - pj1, Z2);
    h2 t10 = __builtin_elementwise_max(pi1 - pj0, Z2);
    h2 t11 = __builtin_elementwise_max(pi1 - pj1, Z2);
    g00 = fdot2(t00, cc, g00);
    g01 = fdot2(t01, cc, g01);
    g10 = fdot2(t10, cc, g10);
    g11 = fdot2(t11, cc, g11);
  }
  // q pre-scaled; softmax without max-shift (scores ~N(0,1), exp safe).
  const float e00 = __expf(s00), e01 = __expf(s01);
  const float e10 = __expf(s10), e11 = __expf(s11);
  {
    h4 w;
    w[0] = (_Float16)e00; w[1] = (_Float16)e01;
    w[2] = (_Float16)e10; w[3] = (_Float16)e11;
    wspi[tid] = w;
  }
  const float wg00 = e00 * g00, wg01 = e01 * g01;
  const float wg10 = e10 * g10, wg11 = e11 * g11;
  float l0 = e00 + e01, l1 = e10 + e11;
  float dx0 = fmaf(wg00, rx00, wg01 * rx01);
  float dy0 = fmaf(wg00, ry00, wg01 * ry01);
  float dx1 = fmaf(wg10, rx10, wg11 * rx11);
  float dy1 = fmaf(wg10, ry10, wg11 * ry11);
#pragma unroll
  for (int off = 32; off > 0; off >>= 1) {
    l0 += __shfl_down(l0, off);
    l1 += __shfl_down(l1, off);
    dx0 += __shfl_down(dx0, off);
    dy0 += __shfl_down(dy0, off);
    dx1 += __shfl_down(dx1, off);
    dy1 += __shfl_down(dy1, off);
  }
  if (lane == 0) {
    red[0][wave] = l0;  red[1][wave] = l1;
    red[2][wave] = dx0; red[3][wave] = dy0;
    red[4][wave] = dx1; red[5][wave] = dy1;
  }
  __syncthreads();  // publishes wspi + red
  float sum0 = 0.f, sum1 = 0.f;
#pragma unroll
  for (int w = 0; w < 8; ++w) { sum0 += red[0][w]; sum1 += red[1][w]; }
  const float inv0 = 1.f / sum0, inv1 = 1.f / sum1;

  if (tid == 0) {
    float DX0 = 0.f, DY0 = 0.f, DX1 = 0.f, DY1 = 0.f;
#pragma unroll
    for (int w = 0; w < 8; ++w) {
      DX0 += red[2][w]; DY0 += red[3][w];
      DX1 += red[4][w]; DY1 += red[5][w];
    }
    out[NN * HH + i0 * 2 + 0] = xi0x + DX0 * inv0;
    out[NN * HH + i0 * 2 + 1] = xi0y + DY0 * inv0;
    out[NN * HH + i1 * 2 + 0] = xi1x + DX1 * inv1;
    out[NN * HH + i1 * 2 + 1] = xi1y + DY1 * inv1;
  }

  // ---- Phase 2: agg_h. wave = j-eighth; 4 j-rows per 16B V load.
  {
    const int j4b = wave * 32;
    const h8* wsp8 = (const h8*)wspi;  // two wspi entries per 16B
    float a0x = 0.f, a0y = 0.f, a1x = 0.f, a1y = 0.f;
#pragma unroll 4
    for (int jj = 0; jj < 32; ++jj) {
      const int j4 = j4b + jj;
      h8 vv = VP[j4 * (HH / 2) + lane];
      h8 wj = wsp8[j4];
      h2 w0a, w1a, w0b, w1b, v0a, v1a, v0b, v1b;
      w0a.x = wj[0]; w0a.y = wj[1];
      w1a.x = wj[2]; w1a.y = wj[3];
      w0b.x = wj[4]; w0b.y = wj[5];
      w1b.x = wj[6]; w1b.y = wj[7];
      v0a.x = vv[0]; v0a.y = vv[1];
      v1a.x = vv[2]; v1a.y = vv[3];
      v0b.x = vv[4]; v0b.y = vv[5];
      v1b.x = vv[6]; v1b.y = vv[7];
      a0x = fdot2(w0a, v0a, a0x);
      a0x = fdot2(w0b, v0b, a0x);
      a0y = fdot2(w0a, v1a, a0y);
      a0y = fdot2(w0b, v1b, a0y);
      a1x = fdot2(w1a, v0a, a1x);
      a1x = fdot2(w1b, v0b, a1x);
      a1y = fdot2(w1a, v1a, a1y);
      a1y = fdot2(w1b, v1b, a1y);
    }
    part[wave][0][2 * lane] = a0x;
    part[wave][0][2 * lane + 1] = a0y;
    part[wave][1][2 * lane] = a1x;
    part[wave][1][2 * lane + 1] = a1y;
  }
  __syncthreads();
  if (tid < 256) {
    const int r = tid >> 7, c = tid & 127;
    float s = 0.f;
#pragma unroll
    for (int g = 0; g < 8; ++g) s += part[g][r][c];
    out[(i0 + r) * HH + c] = h[(i0 + r) * HH + c] + s * (r ? inv1 : inv0);
  }
}

// ------------------------------------------------------------- launch ------
extern "C" void kernel_launch(void* const* d_in, const int* in_sizes, int n_in,
                              void* d_out, int out_size, void* d_ws, size_t ws_size,
                              hipStream_t stream) {
  const float* h   = (const float*)d_in[0];
  const float* x   = (const float*)d_in[1];
  // d_in[2] = batch (int64) — unused (all zeros, reference ignores it)
  const float* Wq  = (const float*)d_in[3];
  const float* bq  = (const float*)d_in[4];
  const float* Wk  = (const float*)d_in[5];
  const float* bk  = (const float*)d_in[6];
  const float* Wv  = (const float*)d_in[7];
  const float* bv  = (const float*)d_in[8];
  const float* We1 = (const float*)d_in[9];
  const float* be1 = (const float*)d_in[10];
  const float* We2 = (const float*)d_in[11];
  const float* be2 = (const float*)d_in[12];
  const float* Wc  = (const float*)d_in[13];
  const float* bc  = (const float*)d_in[14];
  float* out = (float*)d_out;

  float* wsf = (float*)d_ws;
  float* q = wsf;                                   // N*H f32 (pre-scaled)
  _Float16* KP = (_Float16*)(wsf + NN * HH);        // [H/2][N/2] h8
  _Float16* VP = KP + (HH / 2) * (NN / 2) * 8;      // [N/4][H/2] h8
  float* Wc2 = (float*)(VP + (NN / 4) * (HH / 2) * 8);  // H
  float* bc2 = Wc2 + HH;                            // 1

  qkv_kernel<<<257, 512, 0, stream>>>(h, x, Wq, bq, Wk, bk, Wv, bv, We1, We2,
                                      be2, Wc, bc, q, KP, VP, Wc2, bc2);
  attn_kernel<<<512, 512, 0, stream>>>(h, x, q, (const h8*)KP, (const h8*)VP,
                                       be1, Wc2, bc2, out);
}